// Round 8
// baseline (176.218 us; speedup 1.0000x reference)
//
#include <hip/hip_runtime.h>

// Depthwise causal conv1d, k=3.
// x: (8, 768, 4096) fp32, weight: (768, 1, 3) fp32, y: (8, 768, 4096) fp32.
// y[n,c,t] = w[c,0]*x[t-2] + w[c,1]*x[t-1] + w[c,2]*x[t], zeros left of t=0.
//
// v9: fire-and-forget READ path via global_load_lds.
// Evidence: v1/v5/v6/v7/v8 (register-load variants: nt/plain, one-shot/
// persistent, shfl/no-shfl, pinned/unpinned MLP) ALL converge to 55-63 us
// (~2.5 TB/s fabric), while the harness fill sustains 6.8 TB/s at 9%
// occupancy -- stores are fire-and-forget, register loads must stall the
// wave. global_load_lds is the one read mechanism with store-like issue
// semantics: TA streams to LDS, no VGPR round trip; the block issues all
// 16 KB of staging then pays ONE vmcnt drain + barrier.
// Layout: one block per row. Wave w stages chunks {4w..4w+3} (1 KB each,
// lane-contiguous global, linear LDS dest = wave-uniform base + lane*16).
// Compute: thread t owns float4s {t,t+256,t+512,t+768}: ds_read_b128 are
// lane-contiguous 1 KB (2 lanes/bank = conflict-free), history ds_read_b64
// at float 4*f4-2 (8-aligned, 2-way, free). Stores lane-contiguous, plain.
// 16 KB LDS/block -> 8 blocks/CU, full occupancy.

#define CONV_L 4096
#define CONV_C 768

__global__ __launch_bounds__(256) void dwconv1d_k3_lds(
    const float* __restrict__ x,
    const float* __restrict__ w,
    float* __restrict__ y)
{
    __shared__ __align__(16) float xs[CONV_L];   // one full row, 16 KB

    const int row = blockIdx.x;          // 0..6143, block-uniform
    const int c   = row % CONV_C;        // uniform -> scalar weight loads

    const float w0 = w[c * 3 + 0];
    const float w1 = w[c * 3 + 1];
    const float w2 = w[c * 3 + 2];

    const float* xrow = x + (size_t)row * CONV_L;
    float*       yrow = y + (size_t)row * CONV_L;

    const int t    = threadIdx.x;
    const int wv   = t >> 6;             // wave 0..3
    const int lane = t & 63;

    // ---- stage the row: 4 chunks x 1 KB per wave, fire-and-forget ----
#pragma unroll
    for (int k = 0; k < 4; ++k) {
        const int chunk = (wv << 2) + k;                  // wave-uniform
        const float* src = xrow + (chunk << 8) + (lane << 2);
        __builtin_amdgcn_global_load_lds(
            (const __attribute__((address_space(1))) void*)src,
            (__attribute__((address_space(3))) void*)&xs[chunk << 8],
            16, 0, 0);
    }
    __syncthreads();   // compiler emits s_waitcnt vmcnt(0) before s_barrier

    // ---- compute from LDS ----
    const float4* xs4  = (const float4*)xs;
    float4*       yout = (float4*)yrow;

#pragma unroll
    for (int s = 0; s < 4; ++s) {
        const int f4 = t + (s << 8);          // float4 index in the row
        const float4 cur = xs4[f4];

        // history x[4*f4-2], x[4*f4-1]; clamped at the causal row edge
        const float2 h = *(const float2*)&xs[f4 ? ((f4 << 2) - 2) : 0];
        const float m2 = f4 ? h.x : 0.0f;
        const float m1 = f4 ? h.y : 0.0f;

        float4 o;
        o.x = w0 * m2    + w1 * m1    + w2 * cur.x;
        o.y = w0 * m1    + w1 * cur.x + w2 * cur.y;
        o.z = w0 * cur.x + w1 * cur.y + w2 * cur.z;
        o.w = w0 * cur.y + w1 * cur.z + w2 * cur.w;

        yout[f4] = o;
    }
}

extern "C" void kernel_launch(void* const* d_in, const int* in_sizes, int n_in,
                              void* d_out, int out_size, void* d_ws, size_t ws_size,
                              hipStream_t stream)
{
    const float* x = (const float*)d_in[0];
    const float* w = (const float*)d_in[1];
    float* y = (float*)d_out;

    const int rows = out_size / CONV_L;   // out_size is ELEMENTS: 8*768 = 6144
    dwconv1d_k3_lds<<<rows, 256, 0, stream>>>(x, w, y);
}